// Round 1
// baseline (626.777 us; speedup 1.0000x reference)
//
#include <hip/hip_runtime.h>
#include <math.h>

#define B_ 2
#define T_ 1024
#define E_ 1024
#define H_ 16
#define D_ 64
#define M_ (B_*T_)

// ---------------- K0: importance (spike) + alpha ----------------
__global__ __launch_bounds__(256) void imp_alpha_kernel(
    const float* __restrict__ x,
    const float* __restrict__ Wimp, const float* __restrict__ bimp,
    const float* __restrict__ Walpha, const float* __restrict__ balpha,
    const float* __restrict__ thr_p,
    float* __restrict__ spike, float* __restrict__ alpha) {
  int m = blockIdx.x;            // 0..2047  (b*T+t)
  int tid = threadIdx.x;         // 256
  const float* xr = x + (size_t)m * E_;
  float part[17];
#pragma unroll
  for (int i = 0; i < 17; ++i) part[i] = 0.f;
  for (int e = tid; e < E_; e += 256) {
    float xv = xr[e];
    part[16] += xv * Wimp[e];
#pragma unroll
    for (int h = 0; h < 16; ++h) part[h] += xv * Walpha[h * E_ + e];
  }
  __shared__ float red[17][4];
  int lane = tid & 63, wv = tid >> 6;
#pragma unroll
  for (int i = 0; i < 17; ++i) {
    float v = part[i];
    for (int off = 32; off > 0; off >>= 1) v += __shfl_down(v, off, 64);
    if (lane == 0) red[i][wv] = v;
  }
  __syncthreads();
  if (tid < 17) {
    float v = red[tid][0] + red[tid][1] + red[tid][2] + red[tid][3];
    if (tid == 16) {
      float z = v + bimp[0];
      float sig = 1.f / (1.f + expf(-z));
      spike[m] = (sig > thr_p[0]) ? 1.f : 0.f;
    } else {
      float z = v + balpha[tid];
      float a = 1.f / (1.f + expf(-z));
      int b = m >> 10, t = m & (T_ - 1);
      alpha[((size_t)(b * H_ + tid)) * T_ + t] = a;
    }
  }
}

// ---------------- K1: QKV GEMM (f32, 64x64 tiles) ----------------
__global__ __launch_bounds__(256) void qkv_gemm_kernel(
    const float* __restrict__ x, const float* __restrict__ Wqkv,
    const float* __restrict__ bqkv,
    float* __restrict__ q, float* __restrict__ k, float* __restrict__ v) {
  __shared__ float As[16][68];
  __shared__ float Ws[16][68];
  int bn = blockIdx.x;           // 0..47
  int bm = blockIdx.y;           // 0..31
  int tid = threadIdx.x;
  int tx = tid & 15, ty = tid >> 4;
  int lm = tid >> 2;             // 0..63
  int lk = (tid & 3) << 2;       // 0,4,8,12
  int m0 = bm * 64, n0 = bn * 64;
  float acc[4][4] = {{0.f}};
  for (int k0 = 0; k0 < E_; k0 += 16) {
    float4 a4 = *(const float4*)(x + (size_t)(m0 + lm) * E_ + k0 + lk);
    float4 w4 = *(const float4*)(Wqkv + (size_t)(n0 + lm) * E_ + k0 + lk);
    As[lk + 0][lm] = a4.x; As[lk + 1][lm] = a4.y; As[lk + 2][lm] = a4.z; As[lk + 3][lm] = a4.w;
    Ws[lk + 0][lm] = w4.x; Ws[lk + 1][lm] = w4.y; Ws[lk + 2][lm] = w4.z; Ws[lk + 3][lm] = w4.w;
    __syncthreads();
#pragma unroll
    for (int kk = 0; kk < 16; ++kk) {
      float4 a = *(const float4*)&As[kk][ty * 4];
      float4 b = *(const float4*)&Ws[kk][tx * 4];
      float av[4] = {a.x, a.y, a.z, a.w};
      float bv[4] = {b.x, b.y, b.z, b.w};
#pragma unroll
      for (int i = 0; i < 4; ++i)
#pragma unroll
        for (int j = 0; j < 4; ++j) acc[i][j] = fmaf(av[i], bv[j], acc[i][j]);
    }
    __syncthreads();
  }
#pragma unroll
  for (int i = 0; i < 4; ++i) {
    int m = m0 + ty * 4 + i;
    int b = m >> 10, t = m & (T_ - 1);
#pragma unroll
    for (int j = 0; j < 4; ++j) {
      int n = n0 + tx * 4 + j;
      float val = acc[i][j] + bqkv[n];
      int comp = n >> 10, h = (n >> 6) & 15, d = n & 63;
      float* dst = (comp == 0) ? q : ((comp == 1) ? k : v);
      dst[(((size_t)(b * H_ + h)) * T_ + t) * 64 + d] = val;
    }
  }
}

// ---------------- K2: hyperboloid map (expmap0) ----------------
__global__ __launch_bounds__(256) void hyp_kernel(
    const float* __restrict__ q, const float* __restrict__ k,
    const float* __restrict__ qk_scale_p,
    float* __restrict__ qh, float* __restrict__ khn) {
  int wid = blockIdx.x * 4 + (threadIdx.x >> 6);  // 0..65535
  int lane = threadIdx.x & 63;
  int is_k = wid >> 15;
  int row = wid & 32767;                          // (b*H+h)*T + t
  const float* src = (is_k ? k : q) + (size_t)row * 64;
  float u = src[lane];
  float nsq = u * u;
#pragma unroll
  for (int off = 32; off > 0; off >>= 1) nsq += __shfl_xor(nsq, off, 64);
  float norm = fmaxf(sqrtf(nsq), 1e-12f);
  float ss = 1.5f / (1.f + expf(-qk_scale_p[0]));
  float un = u / norm * ss;
  float s2 = un * un;
  float tot = s2;
#pragma unroll
  for (int off = 32; off > 0; off >>= 1) tot += __shfl_xor(tot, off, 64);
  float un0 = __shfl(un, 0, 64);
  float mink = tot - 2.f * un0 * un0;             // -u0^2 + sum_{d>=1} u_d^2
  float nomin = sqrtf(fmaxf(mink, 1e-8f));
  float sc = sinhf(nomin) / nomin;
  float r = sc * un;
  float sp2 = (lane == 0) ? 0.f : r * r;
  float sps = sp2;
#pragma unroll
  for (int off = 32; off > 0; off >>= 1) sps += __shfl_xor(sps, off, 64);
  float tm = sqrtf(1.f + sps);
  float outv = (lane == 0) ? tm : r;
  if (is_k && lane != 0) outv = -outv;            // fold Minkowski sign: dot(qh,khn) = -inner
  (is_k ? khn : qh)[(size_t)row * 64 + lane] = outv;
}

// ---------------- K3: fused dual-geometry flash attention ----------------
#define QBLK 64
#define SBLK 64
__global__ __launch_bounds__(512) void attn_kernel(
    const float* __restrict__ q, const float* __restrict__ k, const float* __restrict__ v,
    const float* __restrict__ qh, const float* __restrict__ khn,
    const float* __restrict__ alpha, const float* __restrict__ spike,
    const float* __restrict__ log_k, float* __restrict__ y) {
  __shared__ float q_s[QBLK][68];
  __shared__ float qh_s[QBLK][68];
  __shared__ float k_s[SBLK][68];
  __shared__ float kh_s[SBLK][68];
  __shared__ float vT_s[64][68];
  __shared__ float p_s[QBLK][68];

  int bid = blockIdx.x;
  int bh = bid & 31;                 // b*H+h
  int qi = 15 - (bid >> 5);          // heavy tiles first
  int b = bh >> 4, h = bh & 15;
  int t0 = qi * QBLK;
  int tid = threadIdx.x;
  int tx = tid & 15;                 // 4 cols each
  int tyr = tid >> 4;                // 0..31, 2 rows each
  int r0 = tyr * 2;
  int c0 = tx * 4;
  const size_t base = ((size_t)bh) * T_ * 64;

  {  // stage Q, Qh once
    int row = tid >> 3;
    int dg = (tid & 7) * 8;
    const float* qp  = q  + base + (size_t)(t0 + row) * 64 + dg;
    const float* qhp = qh + base + (size_t)(t0 + row) * 64 + dg;
    *(float4*)&q_s[row][dg]      = *(const float4*)qp;
    *(float4*)&q_s[row][dg + 4]  = *(const float4*)(qp + 4);
    *(float4*)&qh_s[row][dg]     = *(const float4*)qhp;
    *(float4*)&qh_s[row][dg + 4] = *(const float4*)(qhp + 4);
  }
  float curv = log1pf(expf(log_k[h])) + 1e-6f;
  float inv_curv = 1.f / curv;
  float al[2];
  al[0] = alpha[(size_t)bh * T_ + t0 + r0];
  al[1] = alpha[(size_t)bh * T_ + t0 + r0 + 1];

  float m_r[2] = {-1e30f, -1e30f};
  float l_r[2] = {0.f, 0.f};
  float acc[2][4] = {{0.f}};

  int ntiles = qi + 1;
  for (int st = 0; st < ntiles; ++st) {
    int s0 = st * SBLK;
    __syncthreads();
    {  // stage K, Kh, V^T
      int row = tid >> 3;
      int dg = (tid & 7) * 8;
      const float* kp  = k   + base + (size_t)(s0 + row) * 64 + dg;
      const float* khp = khn + base + (size_t)(s0 + row) * 64 + dg;
      const float* vp  = v   + base + (size_t)(s0 + row) * 64 + dg;
      *(float4*)&k_s[row][dg]      = *(const float4*)kp;
      *(float4*)&k_s[row][dg + 4]  = *(const float4*)(kp + 4);
      *(float4*)&kh_s[row][dg]     = *(const float4*)khp;
      *(float4*)&kh_s[row][dg + 4] = *(const float4*)(khp + 4);
      float4 e = *(const float4*)vp, f = *(const float4*)(vp + 4);
      vT_s[dg + 0][row] = e.x; vT_s[dg + 1][row] = e.y;
      vT_s[dg + 2][row] = e.z; vT_s[dg + 3][row] = e.w;
      vT_s[dg + 4][row] = f.x; vT_s[dg + 5][row] = f.y;
      vT_s[dg + 6][row] = f.z; vT_s[dg + 7][row] = f.w;
    }
    __syncthreads();

    float se[2][4] = {{0.f}}, sh[2][4] = {{0.f}};
    for (int d = 0; d < 64; d += 4) {
      float4 a0 = *(const float4*)&q_s[r0][d];
      float4 a1 = *(const float4*)&q_s[r0 + 1][d];
      float4 h0 = *(const float4*)&qh_s[r0][d];
      float4 h1 = *(const float4*)&qh_s[r0 + 1][d];
#pragma unroll
      for (int j = 0; j < 4; ++j) {
        float4 bb  = *(const float4*)&k_s[c0 + j][d];
        float4 bh4 = *(const float4*)&kh_s[c0 + j][d];
        se[0][j] += a0.x * bb.x + a0.y * bb.y + a0.z * bb.z + a0.w * bb.w;
        se[1][j] += a1.x * bb.x + a1.y * bb.y + a1.z * bb.z + a1.w * bb.w;
        sh[0][j] += h0.x * bh4.x + h0.y * bh4.y + h0.z * bh4.z + h0.w * bh4.w;
        sh[1][j] += h1.x * bh4.x + h1.y * bh4.y + h1.z * bh4.z + h1.w * bh4.w;
      }
    }
    float p[2][4];
#pragma unroll
    for (int i = 0; i < 2; ++i) {
      int t_g = t0 + r0 + i;
      float mx = -1e30f;
#pragma unroll
      for (int j = 0; j < 4; ++j) {
        float sc_e = se[i][j] * 0.125f;                       // 1/sqrt(64)
        float md = fmaxf(sh[i][j], 1.0f + 1e-6f);             // mdot = -inner clamped
        float dist = acoshf(md);
        float sc_h = -dist * dist * inv_curv;
        float s = (1.f - al[i]) * sc_e + al[i] * sc_h;
        if (s0 + c0 + j > t_g) s = -1e30f;                    // causal
        p[i][j] = s;
        mx = fmaxf(mx, s);
      }
      mx = fmaxf(mx, __shfl_xor(mx, 1, 64));
      mx = fmaxf(mx, __shfl_xor(mx, 2, 64));
      mx = fmaxf(mx, __shfl_xor(mx, 4, 64));
      mx = fmaxf(mx, __shfl_xor(mx, 8, 64));
      float m_new = fmaxf(m_r[i], mx);
      float fac = expf(m_r[i] - m_new);
      float ls = 0.f;
#pragma unroll
      for (int j = 0; j < 4; ++j) { p[i][j] = expf(p[i][j] - m_new); ls += p[i][j]; }
      ls += __shfl_xor(ls, 1, 64);
      ls += __shfl_xor(ls, 2, 64);
      ls += __shfl_xor(ls, 4, 64);
      ls += __shfl_xor(ls, 8, 64);
      l_r[i] = l_r[i] * fac + ls;
      m_r[i] = m_new;
#pragma unroll
      for (int j = 0; j < 4; ++j) acc[i][j] *= fac;
      *(float4*)&p_s[r0 + i][c0] = make_float4(p[i][0], p[i][1], p[i][2], p[i][3]);
    }
    __syncthreads();
    for (int s4 = 0; s4 < SBLK; s4 += 4) {
      float4 p0 = *(const float4*)&p_s[r0][s4];
      float4 p1 = *(const float4*)&p_s[r0 + 1][s4];
#pragma unroll
      for (int j = 0; j < 4; ++j) {
        float4 vv = *(const float4*)&vT_s[c0 + j][s4];
        acc[0][j] += p0.x * vv.x + p0.y * vv.y + p0.z * vv.z + p0.w * vv.w;
        acc[1][j] += p1.x * vv.x + p1.y * vv.y + p1.z * vv.z + p1.w * vv.w;
      }
    }
  }
#pragma unroll
  for (int i = 0; i < 2; ++i) {
    int t_g = t0 + r0 + i;
    float sp = spike[(size_t)b * T_ + t_g];
    float invl = sp / l_r[i];
    float* yp = y + ((size_t)(b * T_ + t_g)) * E_ + h * 64 + c0;
    float4 o = make_float4(acc[i][0] * invl, acc[i][1] * invl,
                           acc[i][2] * invl, acc[i][3] * invl);
    *(float4*)yp = o;
  }
}

// ---------------- K4: output projection ----------------
__global__ __launch_bounds__(256) void out_gemm_kernel(
    const float* __restrict__ A, const float* __restrict__ W,
    const float* __restrict__ bias, float* __restrict__ out) {
  __shared__ float As[16][68];
  __shared__ float Ws[16][68];
  int bn = blockIdx.x;           // 0..15
  int bm = blockIdx.y;           // 0..31
  int tid = threadIdx.x;
  int tx = tid & 15, ty = tid >> 4;
  int lm = tid >> 2;
  int lk = (tid & 3) << 2;
  int m0 = bm * 64, n0 = bn * 64;
  float acc[4][4] = {{0.f}};
  for (int k0 = 0; k0 < E_; k0 += 16) {
    float4 a4 = *(const float4*)(A + (size_t)(m0 + lm) * E_ + k0 + lk);
    float4 w4 = *(const float4*)(W + (size_t)(n0 + lm) * E_ + k0 + lk);
    As[lk + 0][lm] = a4.x; As[lk + 1][lm] = a4.y; As[lk + 2][lm] = a4.z; As[lk + 3][lm] = a4.w;
    Ws[lk + 0][lm] = w4.x; Ws[lk + 1][lm] = w4.y; Ws[lk + 2][lm] = w4.z; Ws[lk + 3][lm] = w4.w;
    __syncthreads();
#pragma unroll
    for (int kk = 0; kk < 16; ++kk) {
      float4 a = *(const float4*)&As[kk][ty * 4];
      float4 b = *(const float4*)&Ws[kk][tx * 4];
      float av[4] = {a.x, a.y, a.z, a.w};
      float bv[4] = {b.x, b.y, b.z, b.w};
#pragma unroll
      for (int i = 0; i < 4; ++i)
#pragma unroll
        for (int j = 0; j < 4; ++j) acc[i][j] = fmaf(av[i], bv[j], acc[i][j]);
    }
    __syncthreads();
  }
#pragma unroll
  for (int i = 0; i < 4; ++i) {
    int m = m0 + ty * 4 + i;
#pragma unroll
    for (int j = 0; j < 4; ++j) {
      int n = n0 + tx * 4 + j;
      out[(size_t)m * E_ + n] = acc[i][j] + bias[n];
    }
  }
}

extern "C" void kernel_launch(void* const* d_in, const int* in_sizes, int n_in,
                              void* d_out, int out_size, void* d_ws, size_t ws_size,
                              hipStream_t stream) {
  const float* x      = (const float*)d_in[0];
  const float* Wqkv   = (const float*)d_in[1];
  const float* bqkv   = (const float*)d_in[2];
  const float* Wout   = (const float*)d_in[3];
  const float* bout   = (const float*)d_in[4];
  const float* Wimp   = (const float*)d_in[5];
  const float* bimp   = (const float*)d_in[6];
  const float* Walpha = (const float*)d_in[7];
  const float* balpha = (const float*)d_in[8];
  const float* thr    = (const float*)d_in[9];
  const float* log_k  = (const float*)d_in[10];
  const float* qk_sc  = (const float*)d_in[11];
  float* out = (float*)d_out;

  char* ws = (char*)d_ws;
  size_t off = 0;
  auto alloc = [&](size_t bytes) -> float* {
    float* p = (float*)(ws + off);
    off += (bytes + 255) & ~(size_t)255;
    return p;
  };
  const size_t qkv_bytes = (size_t)B_ * H_ * T_ * D_ * sizeof(float);  // 8 MB
  float* q   = alloc(qkv_bytes);
  float* k   = alloc(qkv_bytes);
  float* v   = alloc(qkv_bytes);
  float* qh  = alloc(qkv_bytes);
  float* khn = alloc(qkv_bytes);
  float* yw  = alloc((size_t)M_ * E_ * sizeof(float));                 // 8 MB
  float* alphaw = alloc((size_t)B_ * H_ * T_ * sizeof(float));
  float* spikew = alloc((size_t)M_ * sizeof(float));

  imp_alpha_kernel<<<M_, 256, 0, stream>>>(x, Wimp, bimp, Walpha, balpha, thr,
                                           spikew, alphaw);
  qkv_gemm_kernel<<<dim3(48, 32), 256, 0, stream>>>(x, Wqkv, bqkv, q, k, v);
  hyp_kernel<<<(2 * B_ * H_ * T_) / 4, 256, 0, stream>>>(q, k, qk_sc, qh, khn);
  attn_kernel<<<B_ * H_ * (T_ / QBLK), 512, 0, stream>>>(q, k, v, qh, khn,
                                                         alphaw, spikew, log_k, yw);
  out_gemm_kernel<<<dim3(16, 32), 256, 0, stream>>>(yw, Wout, bout, out);
}

// Round 2
// 424.621 us; speedup vs baseline: 1.4761x; 1.4761x over previous
//
#include <hip/hip_runtime.h>
#include <math.h>

#define B_ 2
#define T_ 1024
#define E_ 1024
#define H_ 16
#define D_ 64
#define M_ (B_*T_)

typedef __bf16 bf16x8 __attribute__((ext_vector_type(8)));
typedef float f32x4 __attribute__((ext_vector_type(4)));

// swizzled LDS addressing: row-major [64 rows][128 bytes], byte ^= (row&7)<<4
__device__ __forceinline__ void* ldsp(__bf16* base, int row, int byte) {
  return (char*)base + row * 128 + (byte ^ ((row & 7) << 4));
}

// ---------------- K0: importance (spike) + alpha (f32 — sign decision!) ----------------
__global__ __launch_bounds__(256) void imp_alpha_kernel(
    const float* __restrict__ x,
    const float* __restrict__ Wimp, const float* __restrict__ bimp,
    const float* __restrict__ Walpha, const float* __restrict__ balpha,
    const float* __restrict__ thr_p,
    float* __restrict__ spike, float* __restrict__ alpha) {
  int m = blockIdx.x;
  int tid = threadIdx.x;
  const float* xr = x + (size_t)m * E_;
  float part[17];
#pragma unroll
  for (int i = 0; i < 17; ++i) part[i] = 0.f;
  for (int e = tid; e < E_; e += 256) {
    float xv = xr[e];
    part[16] += xv * Wimp[e];
#pragma unroll
    for (int h = 0; h < 16; ++h) part[h] += xv * Walpha[h * E_ + e];
  }
  __shared__ float red[17][4];
  int lane = tid & 63, wv = tid >> 6;
#pragma unroll
  for (int i = 0; i < 17; ++i) {
    float v = part[i];
    for (int off = 32; off > 0; off >>= 1) v += __shfl_down(v, off, 64);
    if (lane == 0) red[i][wv] = v;
  }
  __syncthreads();
  if (tid < 17) {
    float v = red[tid][0] + red[tid][1] + red[tid][2] + red[tid][3];
    if (tid == 16) {
      float z = v + bimp[0];
      float sig = 1.f / (1.f + expf(-z));
      spike[m] = (sig > thr_p[0]) ? 1.f : 0.f;
    } else {
      float z = v + balpha[tid];
      float a = 1.f / (1.f + expf(-z));
      int b = m >> 10, t = m & (T_ - 1);
      alpha[((size_t)(b * H_ + tid)) * T_ + t] = a;
    }
  }
}

// ---------------- K1: QKV GEMM (f32 compute, bf16 outputs) ----------------
__global__ __launch_bounds__(256) void qkv_gemm_kernel(
    const float* __restrict__ x, const float* __restrict__ Wqkv,
    const float* __restrict__ bqkv,
    __bf16* __restrict__ q, __bf16* __restrict__ k, __bf16* __restrict__ v) {
  __shared__ float As[16][68];
  __shared__ float Ws[16][68];
  int bn = blockIdx.x;
  int bm = blockIdx.y;
  int tid = threadIdx.x;
  int tx = tid & 15, ty = tid >> 4;
  int lm = tid >> 2;
  int lk = (tid & 3) << 2;
  int m0 = bm * 64, n0 = bn * 64;
  float acc[4][4] = {{0.f}};
  for (int k0 = 0; k0 < E_; k0 += 16) {
    float4 a4 = *(const float4*)(x + (size_t)(m0 + lm) * E_ + k0 + lk);
    float4 w4 = *(const float4*)(Wqkv + (size_t)(n0 + lm) * E_ + k0 + lk);
    As[lk + 0][lm] = a4.x; As[lk + 1][lm] = a4.y; As[lk + 2][lm] = a4.z; As[lk + 3][lm] = a4.w;
    Ws[lk + 0][lm] = w4.x; Ws[lk + 1][lm] = w4.y; Ws[lk + 2][lm] = w4.z; Ws[lk + 3][lm] = w4.w;
    __syncthreads();
#pragma unroll
    for (int kk = 0; kk < 16; ++kk) {
      float4 a = *(const float4*)&As[kk][ty * 4];
      float4 b = *(const float4*)&Ws[kk][tx * 4];
      float av[4] = {a.x, a.y, a.z, a.w};
      float bv[4] = {b.x, b.y, b.z, b.w};
#pragma unroll
      for (int i = 0; i < 4; ++i)
#pragma unroll
        for (int j = 0; j < 4; ++j) acc[i][j] = fmaf(av[i], bv[j], acc[i][j]);
    }
    __syncthreads();
  }
#pragma unroll
  for (int i = 0; i < 4; ++i) {
    int m = m0 + ty * 4 + i;
    int b = m >> 10, t = m & (T_ - 1);
#pragma unroll
    for (int j = 0; j < 4; ++j) {
      int n = n0 + tx * 4 + j;
      float val = acc[i][j] + bqkv[n];
      int comp = n >> 10, h = (n >> 6) & 15, d = n & 63;
      __bf16* dst = (comp == 0) ? q : ((comp == 1) ? k : v);
      dst[(((size_t)(b * H_ + h)) * T_ + t) * 64 + d] = (__bf16)val;
    }
  }
}

// ---------------- K2: hyperboloid map (bf16 in/out, f32 math) ----------------
__global__ __launch_bounds__(256) void hyp_kernel(
    const __bf16* __restrict__ q, const __bf16* __restrict__ k,
    const float* __restrict__ qk_scale_p,
    __bf16* __restrict__ qh, __bf16* __restrict__ khn) {
  int wid = blockIdx.x * 4 + (threadIdx.x >> 6);
  int lane = threadIdx.x & 63;
  int is_k = wid >> 15;
  int row = wid & 32767;
  const __bf16* src = (is_k ? k : q) + (size_t)row * 64;
  float u = (float)src[lane];
  float nsq = u * u;
#pragma unroll
  for (int off = 32; off > 0; off >>= 1) nsq += __shfl_xor(nsq, off, 64);
  float norm = fmaxf(sqrtf(nsq), 1e-12f);
  float ss = 1.5f / (1.f + expf(-qk_scale_p[0]));
  float un = u / norm * ss;
  float s2 = un * un;
  float tot = s2;
#pragma unroll
  for (int off = 32; off > 0; off >>= 1) tot += __shfl_xor(tot, off, 64);
  float un0 = __shfl(un, 0, 64);
  float mink = tot - 2.f * un0 * un0;
  float nomin = sqrtf(fmaxf(mink, 1e-8f));
  float sc = sinhf(nomin) / nomin;
  float r = sc * un;
  float sp2 = (lane == 0) ? 0.f : r * r;
  float sps = sp2;
#pragma unroll
  for (int off = 32; off > 0; off >>= 1) sps += __shfl_xor(sps, off, 64);
  float tm = sqrtf(1.f + sps);
  float outv = (lane == 0) ? tm : r;
  if (is_k && lane != 0) outv = -outv;  // fold Minkowski sign
  (is_k ? khn : qh)[(size_t)row * 64 + lane] = (__bf16)outv;
}

// ---------------- K3: MFMA dual-geometry flash attention ----------------
// 4 waves x 16 q-rows, QBLK=SBLK=64, 16x16x32 bf16 MFMA
__global__ __launch_bounds__(256) void attn_kernel(
    const __bf16* __restrict__ q, const __bf16* __restrict__ k, const __bf16* __restrict__ v,
    const __bf16* __restrict__ qh, const __bf16* __restrict__ khn,
    const float* __restrict__ alpha, const float* __restrict__ spike,
    const float* __restrict__ log_k, float* __restrict__ y) {
  __shared__ __bf16 q_s[64 * 64];
  __shared__ __bf16 qh_s[64 * 64];
  __shared__ __bf16 k_s[64 * 64];
  __shared__ __bf16 kh_s[64 * 64];
  __shared__ __bf16 vt_s[64 * 64];
  __shared__ __bf16 p_s[64 * 64];

  int bid = blockIdx.x;
  int bh = bid & 31;
  int qi = 15 - (bid >> 5);        // heavy q-tiles first
  int b = bh >> 4, h = bh & 15;
  int t0 = qi * 64;
  int tid = threadIdx.x;
  int w = tid >> 6, lane = tid & 63;
  int lr = lane & 15, g = lane >> 4;
  int trow = w * 16;               // wave's local q-row base
  const size_t base = (size_t)bh * T_ * 64;

  // ---- stage Q, QH (swizzled) ----
#pragma unroll
  for (int it = 0; it < 2; ++it) {
    int task = tid + it * 256;
    int row = task >> 3, cj = task & 7;
    bf16x8 a = *(const bf16x8*)(q + base + (size_t)(t0 + row) * 64 + cj * 8);
    bf16x8 c = *(const bf16x8*)(qh + base + (size_t)(t0 + row) * 64 + cj * 8);
    *(bf16x8*)ldsp(q_s, row, cj * 16) = a;
    *(bf16x8*)ldsp(qh_s, row, cj * 16) = c;
  }

  float curv = log1pf(expf(log_k[h])) + 1e-6f;
  float inv_curv = 1.f / curv;
  int tg[4];
  float al[4], spv[4];
#pragma unroll
  for (int r = 0; r < 4; ++r) {
    tg[r] = t0 + trow + g * 4 + r;
    al[r] = alpha[(size_t)bh * T_ + tg[r]];
    spv[r] = spike[(size_t)b * T_ + tg[r]];
  }

  __syncthreads();
  // hoist Q/QH fragments (A-operand): lane reads row trow+lr, k-chunk g
  bf16x8 aq0 = *(bf16x8*)ldsp(q_s, trow + lr, g * 16);
  bf16x8 aq1 = *(bf16x8*)ldsp(q_s, trow + lr, 64 + g * 16);
  bf16x8 ah0 = *(bf16x8*)ldsp(qh_s, trow + lr, g * 16);
  bf16x8 ah1 = *(bf16x8*)ldsp(qh_s, trow + lr, 64 + g * 16);

  float m_r[4] = {-1e30f, -1e30f, -1e30f, -1e30f};
  float l_r[4] = {0.f, 0.f, 0.f, 0.f};
  f32x4 acc[4];
#pragma unroll
  for (int n = 0; n < 4; ++n) acc[n] = (f32x4){0.f, 0.f, 0.f, 0.f};

  int ntiles = qi + 1;
  for (int st = 0; st < ntiles; ++st) {
    int s0 = st * 64;
    __syncthreads();
    // ---- stage K, KH (swizzled row-major) ----
#pragma unroll
    for (int it = 0; it < 2; ++it) {
      int task = tid + it * 256;
      int row = task >> 3, cj = task & 7;
      bf16x8 a = *(const bf16x8*)(k + base + (size_t)(s0 + row) * 64 + cj * 8);
      bf16x8 c = *(const bf16x8*)(khn + base + (size_t)(s0 + row) * 64 + cj * 8);
      *(bf16x8*)ldsp(k_s, row, cj * 16) = a;
      *(bf16x8*)ldsp(kh_s, row, cj * 16) = c;
    }
    // ---- stage V transposed (vt[d][s], swizzled) ----
#pragma unroll
    for (int it = 0; it < 2; ++it) {
      int task = tid + it * 256;
      int srow = task & 63, dc = task >> 6;
      bf16x8 a = *(const bf16x8*)(v + base + (size_t)(s0 + srow) * 64 + dc * 8);
#pragma unroll
      for (int i = 0; i < 8; ++i)
        *(__bf16*)ldsp(vt_s, dc * 8 + i, srow * 2) = a[i];
    }
    __syncthreads();

    // ---- S = QK^T (euclid) and QH*KHN^T (hyper) via MFMA ----
    f32x4 se[4], sh[4];
#pragma unroll
    for (int j = 0; j < 4; ++j) {
      bf16x8 bk0 = *(bf16x8*)ldsp(k_s, j * 16 + lr, g * 16);
      bf16x8 bk1 = *(bf16x8*)ldsp(k_s, j * 16 + lr, 64 + g * 16);
      f32x4 z = {0.f, 0.f, 0.f, 0.f};
      z = __builtin_amdgcn_mfma_f32_16x16x32_bf16(aq0, bk0, z, 0, 0, 0);
      se[j] = __builtin_amdgcn_mfma_f32_16x16x32_bf16(aq1, bk1, z, 0, 0, 0);
      bf16x8 bh0 = *(bf16x8*)ldsp(kh_s, j * 16 + lr, g * 16);
      bf16x8 bh1 = *(bf16x8*)ldsp(kh_s, j * 16 + lr, 64 + g * 16);
      f32x4 z2 = {0.f, 0.f, 0.f, 0.f};
      z2 = __builtin_amdgcn_mfma_f32_16x16x32_bf16(ah0, bh0, z2, 0, 0, 0);
      sh[j] = __builtin_amdgcn_mfma_f32_16x16x32_bf16(ah1, bh1, z2, 0, 0, 0);
    }

    // ---- blend + causal + online softmax (C layout: row=g*4+r, col=lr+16j) ----
    float pv[4][4];
    float pmax[4] = {-1e30f, -1e30f, -1e30f, -1e30f};
#pragma unroll
    for (int j = 0; j < 4; ++j) {
      int sg = s0 + j * 16 + lr;
#pragma unroll
      for (int r = 0; r < 4; ++r) {
        float sc_e = se[j][r] * 0.125f;
        float md = fmaxf(sh[j][r], 1.0f + 1e-6f);
        float dd = acoshf(md);
        float s = (1.f - al[r]) * sc_e - al[r] * (dd * dd * inv_curv);
        if (sg > tg[r]) s = -1e30f;
        pv[j][r] = s;
        pmax[r] = fmaxf(pmax[r], s);
      }
    }
#pragma unroll
    for (int r = 0; r < 4; ++r) {
      float mx = pmax[r];
      mx = fmaxf(mx, __shfl_xor(mx, 1, 64));
      mx = fmaxf(mx, __shfl_xor(mx, 2, 64));
      mx = fmaxf(mx, __shfl_xor(mx, 4, 64));
      mx = fmaxf(mx, __shfl_xor(mx, 8, 64));
      float mn = fmaxf(m_r[r], mx);
      float fac = __expf(m_r[r] - mn);
      m_r[r] = mn;
      float ls = 0.f;
#pragma unroll
      for (int j = 0; j < 4; ++j) { pv[j][r] = __expf(pv[j][r] - mn); ls += pv[j][r]; }
      ls += __shfl_xor(ls, 1, 64);
      ls += __shfl_xor(ls, 2, 64);
      ls += __shfl_xor(ls, 4, 64);
      ls += __shfl_xor(ls, 8, 64);
      l_r[r] = l_r[r] * fac + ls;
#pragma unroll
      for (int n = 0; n < 4; ++n) acc[n][r] *= fac;
    }
    // ---- write P to LDS (bf16, swizzled) ----
#pragma unroll
    for (int j = 0; j < 4; ++j)
#pragma unroll
      for (int r = 0; r < 4; ++r)
        *(__bf16*)ldsp(p_s, trow + g * 4 + r, (j * 16 + lr) * 2) = (__bf16)pv[j][r];
    __syncthreads();

    // ---- O += P*V ----
    bf16x8 ap0 = *(bf16x8*)ldsp(p_s, trow + lr, g * 16);
    bf16x8 ap1 = *(bf16x8*)ldsp(p_s, trow + lr, 64 + g * 16);
#pragma unroll
    for (int n = 0; n < 4; ++n) {
      bf16x8 bv0 = *(bf16x8*)ldsp(vt_s, n * 16 + lr, g * 16);
      bf16x8 bv1 = *(bf16x8*)ldsp(vt_s, n * 16 + lr, 64 + g * 16);
      acc[n] = __builtin_amdgcn_mfma_f32_16x16x32_bf16(ap0, bv0, acc[n], 0, 0, 0);
      acc[n] = __builtin_amdgcn_mfma_f32_16x16x32_bf16(ap1, bv1, acc[n], 0, 0, 0);
    }
  }

  // ---- epilogue: spike gating + normalize ----
#pragma unroll
  for (int r = 0; r < 4; ++r) {
    float iv = spv[r] / l_r[r];
#pragma unroll
    for (int n = 0; n < 4; ++n) {
      y[((size_t)(b * T_ + tg[r])) * E_ + h * 64 + n * 16 + lr] = acc[n][r] * iv;
    }
  }
}

// ---------------- K4: output projection (f32) ----------------
__global__ __launch_bounds__(256) void out_gemm_kernel(
    const float* __restrict__ A, const float* __restrict__ W,
    const float* __restrict__ bias, float* __restrict__ out) {
  __shared__ float As[16][68];
  __shared__ float Ws[16][68];
  int bn = blockIdx.x;
  int bm = blockIdx.y;
  int tid = threadIdx.x;
  int tx = tid & 15, ty = tid >> 4;
  int lm = tid >> 2;
  int lk = (tid & 3) << 2;
  int m0 = bm * 64, n0 = bn * 64;
  float acc[4][4] = {{0.f}};
  for (int k0 = 0; k0 < E_; k0 += 16) {
    float4 a4 = *(const float4*)(A + (size_t)(m0 + lm) * E_ + k0 + lk);
    float4 w4 = *(const float4*)(W + (size_t)(n0 + lm) * E_ + k0 + lk);
    As[lk + 0][lm] = a4.x; As[lk + 1][lm] = a4.y; As[lk + 2][lm] = a4.z; As[lk + 3][lm] = a4.w;
    Ws[lk + 0][lm] = w4.x; Ws[lk + 1][lm] = w4.y; Ws[lk + 2][lm] = w4.z; Ws[lk + 3][lm] = w4.w;
    __syncthreads();
#pragma unroll
    for (int kk = 0; kk < 16; ++kk) {
      float4 a = *(const float4*)&As[kk][ty * 4];
      float4 b = *(const float4*)&Ws[kk][tx * 4];
      float av[4] = {a.x, a.y, a.z, a.w};
      float bv[4] = {b.x, b.y, b.z, b.w};
#pragma unroll
      for (int i = 0; i < 4; ++i)
#pragma unroll
        for (int j = 0; j < 4; ++j) acc[i][j] = fmaf(av[i], bv[j], acc[i][j]);
    }
    __syncthreads();
  }
#pragma unroll
  for (int i = 0; i < 4; ++i) {
    int m = m0 + ty * 4 + i;
#pragma unroll
    for (int j = 0; j < 4; ++j) {
      int n = n0 + tx * 4 + j;
      out[(size_t)m * E_ + n] = acc[i][j] + bias[n];
    }
  }
}

extern "C" void kernel_launch(void* const* d_in, const int* in_sizes, int n_in,
                              void* d_out, int out_size, void* d_ws, size_t ws_size,
                              hipStream_t stream) {
  const float* x      = (const float*)d_in[0];
  const float* Wqkv   = (const float*)d_in[1];
  const float* bqkv   = (const float*)d_in[2];
  const float* Wout   = (const float*)d_in[3];
  const float* bout   = (const float*)d_in[4];
  const float* Wimp   = (const float*)d_in[5];
  const float* bimp   = (const float*)d_in[6];
  const float* Walpha = (const float*)d_in[7];
  const float* balpha = (const float*)d_in[8];
  const float* thr    = (const float*)d_in[9];
  const float* log_k  = (const float*)d_in[10];
  const float* qk_sc  = (const float*)d_in[11];
  float* out = (float*)d_out;

  char* ws = (char*)d_ws;
  size_t off = 0;
  auto alloc = [&](size_t bytes) -> void* {
    void* p = (void*)(ws + off);
    off += (bytes + 255) & ~(size_t)255;
    return p;
  };
  const size_t qkv_elems = (size_t)B_ * H_ * T_ * D_;
  __bf16* q   = (__bf16*)alloc(qkv_elems * 2);
  __bf16* k   = (__bf16*)alloc(qkv_elems * 2);
  __bf16* v   = (__bf16*)alloc(qkv_elems * 2);
  __bf16* qh  = (__bf16*)alloc(qkv_elems * 2);
  __bf16* khn = (__bf16*)alloc(qkv_elems * 2);
  float* yw   = (float*)alloc((size_t)M_ * E_ * sizeof(float));
  float* alphaw = (float*)alloc((size_t)B_ * H_ * T_ * sizeof(float));
  float* spikew = (float*)alloc((size_t)M_ * sizeof(float));

  imp_alpha_kernel<<<M_, 256, 0, stream>>>(x, Wimp, bimp, Walpha, balpha, thr,
                                           spikew, alphaw);
  qkv_gemm_kernel<<<dim3(48, 32), 256, 0, stream>>>(x, Wqkv, bqkv, q, k, v);
  hyp_kernel<<<(2 * B_ * H_ * T_) / 4, 256, 0, stream>>>(q, k, qk_sc, qh, khn);
  attn_kernel<<<B_ * H_ * (T_ / 64), 256, 0, stream>>>(q, k, v, qh, khn,
                                                       alphaw, spikew, log_k, yw);
  out_gemm_kernel<<<dim3(16, 32), 256, 0, stream>>>(yw, Wout, bout, out);
}

// Round 3
// 151.929 us; speedup vs baseline: 4.1254x; 2.7949x over previous
//
#include <hip/hip_runtime.h>
#include <math.h>

#define B_ 2
#define T_ 1024
#define E_ 1024
#define H_ 16
#define D_ 64
#define M_ (B_*T_)

typedef __bf16 bf16x8 __attribute__((ext_vector_type(8)));
typedef __bf16 bf16x4 __attribute__((ext_vector_type(4)));
typedef float f32x4 __attribute__((ext_vector_type(4)));

// swizzled LDS addressing for attn tiles: row-major [64 rows][128 bytes], byte ^= (row&7)<<4
__device__ __forceinline__ void* ldsp(__bf16* base, int row, int byte) {
  return (char*)base + row * 128 + (byte ^ ((row & 7) << 4));
}

__device__ __forceinline__ void gload_lds16(const void* g, void* l) {
  __builtin_amdgcn_global_load_lds((const __attribute__((address_space(1))) void*)g,
                                   (__attribute__((address_space(3))) void*)l, 16, 0, 0);
}

// ---------------- K-1: f32 -> bf16 conversions (x, Wqkv, Wout) ----------------
#define XV4 524288     // (2*1024*1024)/4
#define WQV4 786432    // (3072*1024)/4
#define WOV4 262144    // (1024*1024)/4
#define TOTV4 (XV4 + WQV4 + WOV4)
__global__ __launch_bounds__(256) void conv_kernel(
    const float* __restrict__ x, const float* __restrict__ Wqkv,
    const float* __restrict__ Wout,
    __bf16* __restrict__ xb, __bf16* __restrict__ Wqkvb, __bf16* __restrict__ Woutb) {
  for (size_t i = (size_t)blockIdx.x * blockDim.x + threadIdx.x; i < TOTV4;
       i += (size_t)gridDim.x * blockDim.x) {
    const float4* src; __bf16* dst; size_t off;
    if (i < XV4)            { src = (const float4*)x;    dst = xb;    off = i; }
    else if (i < XV4+WQV4)  { src = (const float4*)Wqkv; dst = Wqkvb; off = i - XV4; }
    else                    { src = (const float4*)Wout; dst = Woutb; off = i - XV4 - WQV4; }
    float4 val = src[off];
    bf16x4 o = {(__bf16)val.x, (__bf16)val.y, (__bf16)val.z, (__bf16)val.w};
    *(bf16x4*)(dst + off * 4) = o;
  }
}

// ---------------- K0: importance (spike) + alpha (f32 — sign decision!) ----------------
__global__ __launch_bounds__(256) void imp_alpha_kernel(
    const float* __restrict__ x,
    const float* __restrict__ Wimp, const float* __restrict__ bimp,
    const float* __restrict__ Walpha, const float* __restrict__ balpha,
    const float* __restrict__ thr_p,
    float* __restrict__ spike, float* __restrict__ alpha) {
  int m = blockIdx.x;
  int tid = threadIdx.x;
  const float* xr = x + (size_t)m * E_;
  float part[17];
#pragma unroll
  for (int i = 0; i < 17; ++i) part[i] = 0.f;
  for (int e = tid; e < E_; e += 256) {
    float xv = xr[e];
    part[16] += xv * Wimp[e];
#pragma unroll
    for (int h = 0; h < 16; ++h) part[h] += xv * Walpha[h * E_ + e];
  }
  __shared__ float red[17][4];
  int lane = tid & 63, wv = tid >> 6;
#pragma unroll
  for (int i = 0; i < 17; ++i) {
    float v = part[i];
    for (int off = 32; off > 0; off >>= 1) v += __shfl_down(v, off, 64);
    if (lane == 0) red[i][wv] = v;
  }
  __syncthreads();
  if (tid < 17) {
    float v = red[tid][0] + red[tid][1] + red[tid][2] + red[tid][3];
    if (tid == 16) {
      float z = v + bimp[0];
      float sig = 1.f / (1.f + expf(-z));
      spike[m] = (sig > thr_p[0]) ? 1.f : 0.f;
    } else {
      float z = v + balpha[tid];
      float a = 1.f / (1.f + expf(-z));
      int b = m >> 10, t = m & (T_ - 1);
      alpha[((size_t)(b * H_ + tid)) * T_ + t] = a;
    }
  }
}

// ---------------- K1: QKV GEMM — bf16 MFMA, 128x128 tile, m97 structure ----------------
// A = xb [2048][1024], Bm = Wqkvb [3072][1024] (row-major over K), scatter bf16 q/k/v
__global__ __launch_bounds__(256) void qkv_gemm_kernel(
    const __bf16* __restrict__ A, const __bf16* __restrict__ Bm,
    const float* __restrict__ bias,
    __bf16* __restrict__ q, __bf16* __restrict__ k, __bf16* __restrict__ v) {
  __shared__ __bf16 As[128 * 32];
  __shared__ __bf16 Bs[128 * 32];
  const int K = E_;
  int tid = threadIdx.x;
  int w = tid >> 6, lane = tid & 63, lr = lane & 15, g = lane >> 4;
  int m0 = blockIdx.y * 128, n0 = blockIdx.x * 128;
  int wr = (w >> 1) * 64, wc = (w & 1) * 64;

  int task0 = tid, task1 = tid + 256;
  int r0s = task0 >> 2, c0s = task0 & 3;
  int r1s = task1 >> 2, c1s = task1 & 3;
  const __bf16* gA0 = A + (size_t)(m0 + r0s) * K + c0s * 8;
  const __bf16* gA1 = A + (size_t)(m0 + r1s) * K + c1s * 8;
  const __bf16* gB0 = Bm + (size_t)(n0 + r0s) * K + c0s * 8;
  const __bf16* gB1 = Bm + (size_t)(n0 + r1s) * K + c1s * 8;
  __bf16* lA0 = As + task0 * 8;
  __bf16* lA1 = As + task1 * 8;
  __bf16* lB0 = Bs + task0 * 8;
  __bf16* lB1 = Bs + task1 * 8;

  f32x4 acc[4][4];
#pragma unroll
  for (int i = 0; i < 4; ++i)
#pragma unroll
    for (int j = 0; j < 4; ++j) acc[i][j] = (f32x4){0.f, 0.f, 0.f, 0.f};

  for (int k0 = 0; k0 < K; k0 += 32) {
    gload_lds16(gA0, lA0); gload_lds16(gA1, lA1);
    gload_lds16(gB0, lB0); gload_lds16(gB1, lB1);
    gA0 += 32; gA1 += 32; gB0 += 32; gB1 += 32;
    __syncthreads();
    bf16x8 af[4], bf[4];
#pragma unroll
    for (int i = 0; i < 4; ++i) af[i] = *(bf16x8*)&As[(wr + i * 16 + lr) * 32 + g * 8];
#pragma unroll
    for (int j = 0; j < 4; ++j) bf[j] = *(bf16x8*)&Bs[(wc + j * 16 + lr) * 32 + g * 8];
#pragma unroll
    for (int i = 0; i < 4; ++i)
#pragma unroll
      for (int j = 0; j < 4; ++j)
        acc[i][j] = __builtin_amdgcn_mfma_f32_16x16x32_bf16(af[i], bf[j], acc[i][j], 0, 0, 0);
    __syncthreads();
  }

#pragma unroll
  for (int i = 0; i < 4; ++i) {
#pragma unroll
    for (int r = 0; r < 4; ++r) {
      int m = m0 + wr + i * 16 + g * 4 + r;
      int b = m >> 10, t = m & (T_ - 1);
#pragma unroll
      for (int j = 0; j < 4; ++j) {
        int n = n0 + wc + j * 16 + lr;
        float val = acc[i][j][r] + bias[n];
        int comp = n >> 10, h = (n >> 6) & 15, d = n & 63;
        __bf16* dst = (comp == 0) ? q : ((comp == 1) ? k : v);
        dst[(((size_t)(b * H_ + h)) * T_ + t) * 64 + d] = (__bf16)val;
      }
    }
  }
}

// ---------------- K2: hyperboloid map (bf16 in/out, f32 math) ----------------
__global__ __launch_bounds__(256) void hyp_kernel(
    const __bf16* __restrict__ q, const __bf16* __restrict__ k,
    const float* __restrict__ qk_scale_p,
    __bf16* __restrict__ qh, __bf16* __restrict__ khn) {
  int wid = blockIdx.x * 4 + (threadIdx.x >> 6);
  int lane = threadIdx.x & 63;
  int is_k = wid >> 15;
  int row = wid & 32767;
  const __bf16* src = (is_k ? k : q) + (size_t)row * 64;
  float u = (float)src[lane];
  float nsq = u * u;
#pragma unroll
  for (int off = 32; off > 0; off >>= 1) nsq += __shfl_xor(nsq, off, 64);
  float norm = fmaxf(sqrtf(nsq), 1e-12f);
  float ss = 1.5f / (1.f + expf(-qk_scale_p[0]));
  float un = u / norm * ss;
  float s2 = un * un;
  float tot = s2;
#pragma unroll
  for (int off = 32; off > 0; off >>= 1) tot += __shfl_xor(tot, off, 64);
  float un0 = __shfl(un, 0, 64);
  float mink = tot - 2.f * un0 * un0;
  float nomin = sqrtf(fmaxf(mink, 1e-8f));
  float sc = sinhf(nomin) / nomin;
  float r = sc * un;
  float sp2 = (lane == 0) ? 0.f : r * r;
  float sps = sp2;
#pragma unroll
  for (int off = 32; off > 0; off >>= 1) sps += __shfl_xor(sps, off, 64);
  float tm = sqrtf(1.f + sps);
  float outv = (lane == 0) ? tm : r;
  if (is_k && lane != 0) outv = -outv;  // fold Minkowski sign
  (is_k ? khn : qh)[(size_t)row * 64 + lane] = (__bf16)outv;
}

// ---------------- K3: MFMA dual-geometry flash attention ----------------
__global__ __launch_bounds__(256) void attn_kernel(
    const __bf16* __restrict__ q, const __bf16* __restrict__ k, const __bf16* __restrict__ v,
    const __bf16* __restrict__ qh, const __bf16* __restrict__ khn,
    const float* __restrict__ alpha, const float* __restrict__ spike,
    const float* __restrict__ log_k, __bf16* __restrict__ y) {
  __shared__ __bf16 q_s[64 * 64];
  __shared__ __bf16 qh_s[64 * 64];
  __shared__ __bf16 k_s[64 * 64];
  __shared__ __bf16 kh_s[64 * 64];
  __shared__ __bf16 vt_s[64 * 64];
  __shared__ __bf16 p_s[64 * 64];

  int bid = blockIdx.x;
  int bh = bid & 31;
  int qi = 15 - (bid >> 5);        // heavy q-tiles first
  int b = bh >> 4, h = bh & 15;
  int t0 = qi * 64;
  int tid = threadIdx.x;
  int w = tid >> 6, lane = tid & 63;
  int lr = lane & 15, g = lane >> 4;
  int trow = w * 16;
  const size_t base = (size_t)bh * T_ * 64;

#pragma unroll
  for (int it = 0; it < 2; ++it) {
    int task = tid + it * 256;
    int row = task >> 3, cj = task & 7;
    bf16x8 a = *(const bf16x8*)(q + base + (size_t)(t0 + row) * 64 + cj * 8);
    bf16x8 c = *(const bf16x8*)(qh + base + (size_t)(t0 + row) * 64 + cj * 8);
    *(bf16x8*)ldsp(q_s, row, cj * 16) = a;
    *(bf16x8*)ldsp(qh_s, row, cj * 16) = c;
  }

  float curv = log1pf(expf(log_k[h])) + 1e-6f;
  float inv_curv = 1.f / curv;
  int tg[4];
  float al[4], spv[4];
#pragma unroll
  for (int r = 0; r < 4; ++r) {
    tg[r] = t0 + trow + g * 4 + r;
    al[r] = alpha[(size_t)bh * T_ + tg[r]];
    spv[r] = spike[(size_t)b * T_ + tg[r]];
  }

  __syncthreads();
  bf16x8 aq0 = *(bf16x8*)ldsp(q_s, trow + lr, g * 16);
  bf16x8 aq1 = *(bf16x8*)ldsp(q_s, trow + lr, 64 + g * 16);
  bf16x8 ah0 = *(bf16x8*)ldsp(qh_s, trow + lr, g * 16);
  bf16x8 ah1 = *(bf16x8*)ldsp(qh_s, trow + lr, 64 + g * 16);

  float m_r[4] = {-1e30f, -1e30f, -1e30f, -1e30f};
  float l_r[4] = {0.f, 0.f, 0.f, 0.f};
  f32x4 acc[4];
#pragma unroll
  for (int n = 0; n < 4; ++n) acc[n] = (f32x4){0.f, 0.f, 0.f, 0.f};

  int ntiles = qi + 1;
  for (int st = 0; st < ntiles; ++st) {
    int s0 = st * 64;
    __syncthreads();
#pragma unroll
    for (int it = 0; it < 2; ++it) {
      int task = tid + it * 256;
      int row = task >> 3, cj = task & 7;
      bf16x8 a = *(const bf16x8*)(k + base + (size_t)(s0 + row) * 64 + cj * 8);
      bf16x8 c = *(const bf16x8*)(khn + base + (size_t)(s0 + row) * 64 + cj * 8);
      *(bf16x8*)ldsp(k_s, row, cj * 16) = a;
      *(bf16x8*)ldsp(kh_s, row, cj * 16) = c;
    }
#pragma unroll
    for (int it = 0; it < 2; ++it) {
      int task = tid + it * 256;
      int srow = task & 63, dc = task >> 6;
      bf16x8 a = *(const bf16x8*)(v + base + (size_t)(s0 + srow) * 64 + dc * 8);
#pragma unroll
      for (int i = 0; i < 8; ++i)
        *(__bf16*)ldsp(vt_s, dc * 8 + i, srow * 2) = a[i];
    }
    __syncthreads();

    f32x4 se[4], sh[4];
#pragma unroll
    for (int j = 0; j < 4; ++j) {
      bf16x8 bk0 = *(bf16x8*)ldsp(k_s, j * 16 + lr, g * 16);
      bf16x8 bk1 = *(bf16x8*)ldsp(k_s, j * 16 + lr, 64 + g * 16);
      f32x4 z = {0.f, 0.f, 0.f, 0.f};
      z = __builtin_amdgcn_mfma_f32_16x16x32_bf16(aq0, bk0, z, 0, 0, 0);
      se[j] = __builtin_amdgcn_mfma_f32_16x16x32_bf16(aq1, bk1, z, 0, 0, 0);
      bf16x8 bh0 = *(bf16x8*)ldsp(kh_s, j * 16 + lr, g * 16);
      bf16x8 bh1 = *(bf16x8*)ldsp(kh_s, j * 16 + lr, 64 + g * 16);
      f32x4 z2 = {0.f, 0.f, 0.f, 0.f};
      z2 = __builtin_amdgcn_mfma_f32_16x16x32_bf16(ah0, bh0, z2, 0, 0, 0);
      sh[j] = __builtin_amdgcn_mfma_f32_16x16x32_bf16(ah1, bh1, z2, 0, 0, 0);
    }

    float pv[4][4];
    float pmax[4] = {-1e30f, -1e30f, -1e30f, -1e30f};
#pragma unroll
    for (int j = 0; j < 4; ++j) {
      int sg = s0 + j * 16 + lr;
#pragma unroll
      for (int r = 0; r < 4; ++r) {
        float sc_e = se[j][r] * 0.125f;
        float md = fmaxf(sh[j][r], 1.0f + 1e-6f);
        float dd = __logf(md + sqrtf(md * md - 1.f));   // acosh, fast path
        float s = (1.f - al[r]) * sc_e - al[r] * (dd * dd * inv_curv);
        if (sg > tg[r]) s = -1e30f;
        pv[j][r] = s;
        pmax[r] = fmaxf(pmax[r], s);
      }
    }
#pragma unroll
    for (int r = 0; r < 4; ++r) {
      float mx = pmax[r];
      mx = fmaxf(mx, __shfl_xor(mx, 1, 64));
      mx = fmaxf(mx, __shfl_xor(mx, 2, 64));
      mx = fmaxf(mx, __shfl_xor(mx, 4, 64));
      mx = fmaxf(mx, __shfl_xor(mx, 8, 64));
      float mn = fmaxf(m_r[r], mx);
      float fac = __expf(m_r[r] - mn);
      m_r[r] = mn;
      float ls = 0.f;
#pragma unroll
      for (int j = 0; j < 4; ++j) { pv[j][r] = __expf(pv[j][r] - mn); ls += pv[j][r]; }
      ls += __shfl_xor(ls, 1, 64);
      ls += __shfl_xor(ls, 2, 64);
      ls += __shfl_xor(ls, 4, 64);
      ls += __shfl_xor(ls, 8, 64);
      l_r[r] = l_r[r] * fac + ls;
#pragma unroll
      for (int n = 0; n < 4; ++n) acc[n][r] *= fac;
    }
#pragma unroll
    for (int j = 0; j < 4; ++j)
#pragma unroll
      for (int r = 0; r < 4; ++r)
        *(__bf16*)ldsp(p_s, trow + g * 4 + r, (j * 16 + lr) * 2) = (__bf16)pv[j][r];
    __syncthreads();

    bf16x8 ap0 = *(bf16x8*)ldsp(p_s, trow + lr, g * 16);
    bf16x8 ap1 = *(bf16x8*)ldsp(p_s, trow + lr, 64 + g * 16);
#pragma unroll
    for (int n = 0; n < 4; ++n) {
      bf16x8 bv0 = *(bf16x8*)ldsp(vt_s, n * 16 + lr, g * 16);
      bf16x8 bv1 = *(bf16x8*)ldsp(vt_s, n * 16 + lr, 64 + g * 16);
      acc[n] = __builtin_amdgcn_mfma_f32_16x16x32_bf16(ap0, bv0, acc[n], 0, 0, 0);
      acc[n] = __builtin_amdgcn_mfma_f32_16x16x32_bf16(ap1, bv1, acc[n], 0, 0, 0);
    }
  }

#pragma unroll
  for (int r = 0; r < 4; ++r) {
    float iv = spv[r] / l_r[r];
#pragma unroll
    for (int n = 0; n < 4; ++n) {
      y[((size_t)(b * T_ + tg[r])) * E_ + h * 64 + n * 16 + lr] =
          (__bf16)(acc[n][r] * iv);
    }
  }
}

// ---------------- K4: output projection — bf16 MFMA, f32 out ----------------
__global__ __launch_bounds__(256) void out_gemm_kernel(
    const __bf16* __restrict__ A, const __bf16* __restrict__ Bm,
    const float* __restrict__ bias, float* __restrict__ outp) {
  __shared__ __bf16 As[128 * 32];
  __shared__ __bf16 Bs[128 * 32];
  const int K = E_;
  int tid = threadIdx.x;
  int w = tid >> 6, lane = tid & 63, lr = lane & 15, g = lane >> 4;
  int m0 = blockIdx.y * 128, n0 = blockIdx.x * 128;
  int wr = (w >> 1) * 64, wc = (w & 1) * 64;

  int task0 = tid, task1 = tid + 256;
  int r0s = task0 >> 2, c0s = task0 & 3;
  int r1s = task1 >> 2, c1s = task1 & 3;
  const __bf16* gA0 = A + (size_t)(m0 + r0s) * K + c0s * 8;
  const __bf16* gA1 = A + (size_t)(m0 + r1s) * K + c1s * 8;
  const __bf16* gB0 = Bm + (size_t)(n0 + r0s) * K + c0s * 8;
  const __bf16* gB1 = Bm + (size_t)(n0 + r1s) * K + c1s * 8;
  __bf16* lA0 = As + task0 * 8;
  __bf16* lA1 = As + task1 * 8;
  __bf16* lB0 = Bs + task0 * 8;
  __bf16* lB1 = Bs + task1 * 8;

  f32x4 acc[4][4];
#pragma unroll
  for (int i = 0; i < 4; ++i)
#pragma unroll
    for (int j = 0; j < 4; ++j) acc[i][j] = (f32x4){0.f, 0.f, 0.f, 0.f};

  for (int k0 = 0; k0 < K; k0 += 32) {
    gload_lds16(gA0, lA0); gload_lds16(gA1, lA1);
    gload_lds16(gB0, lB0); gload_lds16(gB1, lB1);
    gA0 += 32; gA1 += 32; gB0 += 32; gB1 += 32;
    __syncthreads();
    bf16x8 af[4], bf[4];
#pragma unroll
    for (int i = 0; i < 4; ++i) af[i] = *(bf16x8*)&As[(wr + i * 16 + lr) * 32 + g * 8];
#pragma unroll
    for (int j = 0; j < 4; ++j) bf[j] = *(bf16x8*)&Bs[(wc + j * 16 + lr) * 32 + g * 8];
#pragma unroll
    for (int i = 0; i < 4; ++i)
#pragma unroll
      for (int j = 0; j < 4; ++j)
        acc[i][j] = __builtin_amdgcn_mfma_f32_16x16x32_bf16(af[i], bf[j], acc[i][j], 0, 0, 0);
    __syncthreads();
  }

#pragma unroll
  for (int i = 0; i < 4; ++i) {
#pragma unroll
    for (int r = 0; r < 4; ++r) {
      int m = m0 + wr + i * 16 + g * 4 + r;
#pragma unroll
      for (int j = 0; j < 4; ++j) {
        int n = n0 + wc + j * 16 + lr;
        outp[(size_t)m * E_ + n] = acc[i][j][r] + bias[n];
      }
    }
  }
}

extern "C" void kernel_launch(void* const* d_in, const int* in_sizes, int n_in,
                              void* d_out, int out_size, void* d_ws, size_t ws_size,
                              hipStream_t stream) {
  const float* x      = (const float*)d_in[0];
  const float* Wqkv   = (const float*)d_in[1];
  const float* bqkv   = (const float*)d_in[2];
  const float* Wout   = (const float*)d_in[3];
  const float* bout   = (const float*)d_in[4];
  const float* Wimp   = (const float*)d_in[5];
  const float* bimp   = (const float*)d_in[6];
  const float* Walpha = (const float*)d_in[7];
  const float* balpha = (const float*)d_in[8];
  const float* thr    = (const float*)d_in[9];
  const float* log_k  = (const float*)d_in[10];
  const float* qk_sc  = (const float*)d_in[11];
  float* out = (float*)d_out;

  char* ws = (char*)d_ws;
  size_t off = 0;
  auto alloc = [&](size_t bytes) -> void* {
    void* p = (void*)(ws + off);
    off += (bytes + 255) & ~(size_t)255;
    return p;
  };
  const size_t qkv_elems = (size_t)B_ * H_ * T_ * D_;
  __bf16* xb    = (__bf16*)alloc((size_t)M_ * E_ * 2);
  __bf16* Wqkvb = (__bf16*)alloc((size_t)3 * E_ * E_ * 2);
  __bf16* Woutb = (__bf16*)alloc((size_t)E_ * E_ * 2);
  __bf16* q   = (__bf16*)alloc(qkv_elems * 2);
  __bf16* k   = (__bf16*)alloc(qkv_elems * 2);
  __bf16* v   = (__bf16*)alloc(qkv_elems * 2);
  __bf16* qh  = (__bf16*)alloc(qkv_elems * 2);
  __bf16* khn = (__bf16*)alloc(qkv_elems * 2);
  __bf16* yw  = (__bf16*)alloc((size_t)M_ * E_ * 2);
  float* alphaw = (float*)alloc((size_t)B_ * H_ * T_ * sizeof(float));
  float* spikew = (float*)alloc((size_t)M_ * sizeof(float));

  conv_kernel<<<1024, 256, 0, stream>>>(x, Wqkv, Wout, xb, Wqkvb, Woutb);
  imp_alpha_kernel<<<M_, 256, 0, stream>>>(x, Wimp, bimp, Walpha, balpha, thr,
                                           spikew, alphaw);
  qkv_gemm_kernel<<<dim3(24, 16), 256, 0, stream>>>(xb, Wqkvb, bqkv, q, k, v);
  hyp_kernel<<<(2 * B_ * H_ * T_) / 4, 256, 0, stream>>>(q, k, qk_sc, qh, khn);
  attn_kernel<<<B_ * H_ * (T_ / 64), 256, 0, stream>>>(q, k, v, qh, khn,
                                                       alphaw, spikew, log_k, yw);
  out_gemm_kernel<<<dim3(8, 16), 256, 0, stream>>>(yw, Woutb, bout, out);
}